// Round 12
// baseline (661.906 us; speedup 1.0000x reference)
//
#include <hip/hip_runtime.h>
#include <hip/hip_bf16.h>
#include <hip/hip_fp16.h>

#define N_NODES 100000
#define N_EDGES 1600000
#define E_SL (N_EDGES + N_NODES)
#define HID 64
#define NUM_GRAPHS 64
#define NEG_SLOPE 0.2f
#define SCAN_CHUNK 1024
#define SCAN_NB ((N_NODES + SCAN_CHUNK - 1) / SCAN_CHUNK)
// CSR row: 8 words = 32B, line-aligned:
// w0=ale0.h01 w1=ale0.h23 w2=ale1.h01 w3=ale1.h23 w4=ale2.h01 w5=ale2.h23 w6=src w7=pad
#define ROW_W 8
#define XP_NODES_PER_BLK 16
#define POOL_NODES_PER_BLK 256

// ============ CSR build (once per call, reused by all 3 layers) ============

// 4 edges/thread: 4 independent random-atomic chains in flight (R11: 1 chain,
// VALUBusy 2.9%, latency-bound at 96us).
__global__ void hist_kernel(const int* __restrict__ ei, int* __restrict__ cnt) {
    int base = blockIdx.x * 1024 + threadIdx.x;
    #pragma unroll
    for (int u = 0; u < 4; ++u) {
        int e = base + u * 256;
        if (e < N_EDGES) atomicAdd(&cnt[ei[N_EDGES + e]], 1);
    }
}

__global__ void scan_local_kernel(const int* __restrict__ cnt, int* __restrict__ row_ptr,
                                  int* __restrict__ bsum) {
    __shared__ int s[256];
    int t = threadIdx.x;
    int base = blockIdx.x * SCAN_CHUNK + t * 4;
    int v[4]; int sum = 0;
    #pragma unroll
    for (int i = 0; i < 4; ++i) {
        int idx = base + i;
        v[i] = (idx < N_NODES) ? cnt[idx] + 1 : 0;
        sum += v[i];
    }
    s[t] = sum;
    __syncthreads();
    for (int off = 1; off < 256; off <<= 1) {
        int x = (t >= off) ? s[t - off] : 0;
        __syncthreads();
        s[t] += x;
        __syncthreads();
    }
    int run = s[t] - sum;
    #pragma unroll
    for (int i = 0; i < 4; ++i) {
        int idx = base + i;
        if (idx < N_NODES) row_ptr[idx] = run;
        run += v[i];
    }
    if (t == 255) bsum[blockIdx.x] = s[255];
}

__global__ void scan_bsum_kernel(int* __restrict__ bsum) {
    if (threadIdx.x != 0) return;
    int acc = 0;
    for (int i = 0; i < SCAN_NB; ++i) { int v = bsum[i]; bsum[i] = acc; acc += v; }
}

__global__ void scan_add_kernel(int* __restrict__ row_ptr, const int* __restrict__ bsum) {
    int i = blockIdx.x * blockDim.x + threadIdx.x;
    if (i > N_NODES) return;
    if (i == N_NODES) row_ptr[i] = E_SL;
    else row_ptr[i] += bsum[i >> 10];
}

// fold We (8x64) + att_e (4x16) into weff[layer][8][4] for all 3 layers.
__global__ void weff_all_kernel(const float* __restrict__ We0, const float* __restrict__ ae0,
                                const float* __restrict__ Weh, const float* __restrict__ aeh,
                                float* __restrict__ weff) {
    int t = threadIdx.x;
    if (t >= 96) return;
    int layer = t >> 5, r = t & 31;
    int dd = r >> 2, h = r & 3;
    const float* We = (layer == 0) ? We0 : Weh + (size_t)(layer - 1) * 8 * 64;
    const float* ae = (layer == 0) ? ae0 : aeh + (size_t)(layer - 1) * 64;
    float s = 0.f;
    #pragma unroll
    for (int c = 0; c < 16; ++c) s += We[dd * 64 + h * 16 + c] * ae[h * 16 + c];
    weff[layer * 32 + dd * 4 + h] = s;
}

// CSR build v4: FOUR edges per thread. Per edge: precompute ale[l][h] =
// ea . weff[l][:,h] for all 3 layers, pack to half, write one 32B aligned
// row. The 4 edges' loads / atomics / stores are independent -> 4 random
// chains in flight per thread (R11 was 1 chain, latency-bound: 96us at
// VALUBusy 2.9%, 52% occupancy). WRITE ~= 1 line/edge is the scatter floor.
__global__ void build_csr_kernel(const int* __restrict__ ei, const float* __restrict__ ea,
                                 const int* __restrict__ row_ptr, int* __restrict__ cursor,
                                 const float* __restrict__ weff,
                                 unsigned int* __restrict__ ale_csr) {
    int base = blockIdx.x * 1024 + threadIdx.x;
    int e[4]; int valid = 0;
    #pragma unroll
    for (int u = 0; u < 4; ++u) {
        e[u] = base + u * 256;
        if (e[u] < N_EDGES) valid = u + 1;
    }
    int src[4], d[4];
    float4 a0[4], a1[4];
    #pragma unroll
    for (int u = 0; u < 4; ++u) {
        if (u < valid) {
            src[u] = ei[e[u]];
            d[u]   = ei[N_EDGES + e[u]];
            a0[u] = *(const float4*)(ea + (size_t)e[u] * 8);
            a1[u] = *(const float4*)(ea + (size_t)e[u] * 8 + 4);
        }
    }
    unsigned int w[4][8];
    #pragma unroll
    for (int u = 0; u < 4; ++u) {
        if (u < valid) {
            float av[8] = {a0[u].x, a0[u].y, a0[u].z, a0[u].w,
                           a1[u].x, a1[u].y, a1[u].z, a1[u].w};
            #pragma unroll
            for (int l = 0; l < 3; ++l) {
                float al[4];
                #pragma unroll
                for (int h = 0; h < 4; ++h) {
                    float s = 0.f;
                    #pragma unroll
                    for (int j = 0; j < 8; ++j) s += av[j] * weff[l * 32 + j * 4 + h];
                    al[h] = s;
                }
                __half2 p01 = __floats2half2_rn(al[0], al[1]);
                __half2 p23 = __floats2half2_rn(al[2], al[3]);
                w[u][2 * l]     = *(unsigned int*)&p01;
                w[u][2 * l + 1] = *(unsigned int*)&p23;
            }
            w[u][6] = (unsigned int)src[u];
            w[u][7] = 0u;
        }
    }
    int pos[4];
    #pragma unroll
    for (int u = 0; u < 4; ++u)
        if (u < valid) pos[u] = row_ptr[d[u]] + atomicAdd(&cursor[d[u]], 1);
    #pragma unroll
    for (int u = 0; u < 4; ++u) {
        if (u < valid) {
            unsigned int* rowp = ale_csr + (size_t)pos[u] * ROW_W;
            *(uint4*)rowp       = make_uint4(w[u][0], w[u][1], w[u][2], w[u][3]);
            *(uint4*)(rowp + 4) = make_uint4(w[u][4], w[u][5], w[u][6], w[u][7]);
        }
    }
}

// self-loop row (last slot per segment) = MEAN of incoming ale rows (valid by
// linearity) + src=n. 2 threads/node.
__global__ void mean_ea_kernel(const int* __restrict__ row_ptr,
                               unsigned int* __restrict__ ale_csr) {
    int idx = blockIdx.x * blockDim.x + threadIdx.x;
    if (idx >= N_NODES * 2) return;
    int n = idx >> 1, part = idx & 1;
    int start = row_ptr[n], last = row_ptr[n + 1] - 1;
    float inv = 1.f / fmaxf((float)(last - start), 1.f);
    if (part == 0) {
        float s[8] = {0.f, 0.f, 0.f, 0.f, 0.f, 0.f, 0.f, 0.f};
        for (int pos = start; pos < last; ++pos) {
            uint4 v = *(const uint4*)(ale_csr + (size_t)pos * ROW_W);
            float2 f0 = __half22float2(*(const __half2*)&v.x);
            float2 f1 = __half22float2(*(const __half2*)&v.y);
            float2 f2 = __half22float2(*(const __half2*)&v.z);
            float2 f3 = __half22float2(*(const __half2*)&v.w);
            s[0] += f0.x; s[1] += f0.y; s[2] += f1.x; s[3] += f1.y;
            s[4] += f2.x; s[5] += f2.y; s[6] += f3.x; s[7] += f3.y;
        }
        __half2 p0 = __floats2half2_rn(s[0] * inv, s[1] * inv);
        __half2 p1 = __floats2half2_rn(s[2] * inv, s[3] * inv);
        __half2 p2 = __floats2half2_rn(s[4] * inv, s[5] * inv);
        __half2 p3 = __floats2half2_rn(s[6] * inv, s[7] * inv);
        *(uint4*)(ale_csr + (size_t)last * ROW_W) =
            make_uint4(*(unsigned int*)&p0, *(unsigned int*)&p1,
                       *(unsigned int*)&p2, *(unsigned int*)&p3);
    } else {
        float s[4] = {0.f, 0.f, 0.f, 0.f};
        for (int pos = start; pos < last; ++pos) {
            uint2 v = *(const uint2*)(ale_csr + (size_t)pos * ROW_W + 4);
            float2 f0 = __half22float2(*(const __half2*)&v.x);
            float2 f1 = __half22float2(*(const __half2*)&v.y);
            s[0] += f0.x; s[1] += f0.y; s[2] += f1.x; s[3] += f1.y;
        }
        __half2 p0 = __floats2half2_rn(s[0] * inv, s[1] * inv);
        __half2 p1 = __floats2half2_rn(s[2] * inv, s[3] * inv);
        uint4 w = make_uint4(*(unsigned int*)&p0, *(unsigned int*)&p1,
                             (unsigned int)n, 0u);
        *(uint4*)(ale_csr + (size_t)last * ROW_W + 4) = w;
    }
}

// ============ per-layer kernels ============

// xp = x @ W (output FP16); als/ald fp32. One wave per block; W column in
// VGPRs, wave-uniform x-row loads.
template <int FIN>
__global__ __launch_bounds__(64) void xp_kernel(
    const float* __restrict__ xin, const float* __restrict__ W,
    const float* __restrict__ a_s, const float* __restrict__ a_d,
    __half* __restrict__ xp, float* __restrict__ als, float* __restrict__ ald) {
    int lane = threadIdx.x;
    float wcol[FIN];
    #pragma unroll
    for (int k = 0; k < FIN; ++k) wcol[k] = W[k * 64 + lane];
    float asl = a_s[lane], adl = a_d[lane];
    int n0 = blockIdx.x * XP_NODES_PER_BLK;
    #pragma unroll 1
    for (int ni = 0; ni < XP_NODES_PER_BLK; ++ni) {
        int n = n0 + ni;
        if (n >= N_NODES) return;
        const float* xr = xin + (size_t)n * FIN;
        float a0 = 0.f, a1 = 0.f, a2 = 0.f, a3 = 0.f;
        #pragma unroll
        for (int k = 0; k < FIN; k += 4) {
            float4 xv = *(const float4*)(xr + k);
            a0 += xv.x * wcol[k];     a1 += xv.y * wcol[k + 1];
            a2 += xv.z * wcol[k + 2]; a3 += xv.w * wcol[k + 3];
        }
        float acc = (a0 + a1) + (a2 + a3);
        xp[(size_t)n * 64 + lane] = __float2half(acc);
        float ps = acc * asl, pd = acc * adl;
        #pragma unroll
        for (int mk = 8; mk >= 1; mk >>= 1) {
            ps += __shfl_xor(ps, mk, 16);
            pd += __shfl_xor(pd, mk, 16);
        }
        if ((lane & 15) == 0) {
            als[(size_t)n * 4 + (lane >> 4)] = ps;
            ald[(size_t)n * 4 + (lane >> 4)] = pd;
        }
    }
}

// Fused GAT, one wave per node. NO max-subtraction (|logit| << 88 -> expf
// cannot overflow; identical up to rounding). Phase 1: lane = edge
// (precomputed half ale from CSR row); ex + src staged in LDS (gather
// addresses from LDS/lgkmcnt, not global/vmcnt -- R8 lesson).
// Phase 3: lane = (column-quad cq, subgroup eg); round-up stride-16 loop ->
// always 4 independent fp16 row gathers in flight, no tail.
__global__ __launch_bounds__(256) void gat_node_kernel(
    const int* __restrict__ row_ptr, const unsigned int* __restrict__ ale_csr,
    const float* __restrict__ als, const float* __restrict__ ald,
    const __half* __restrict__ xp, int layer,
    float* __restrict__ out, const float* __restrict__ bias, int relu_flag) {
    __shared__ float exl[4 * 256];   // per-wave: 64 edges x 4 heads
    __shared__ int   coll[4 * 64];   // per-wave: 64 src ids
    int wave = threadIdx.x >> 6, lane = threadIdx.x & 63;
    int node = blockIdx.x * 4 + wave;
    if (node >= N_NODES) return;
    int start = row_ptr[node], end = row_ptr[node + 1];
    int deg = end - start;                       // >= 1 (self-loop)
    int wb = wave * 64, wb4 = wave * 256;
    int cq = lane & 15;                          // column quad: cols 4cq..4cq+3
    int eg = lane >> 4;                          // edge subgroup 0..3
    int hv = cq >> 2;                            // head for this column quad

    float4 ad4 = *(const float4*)(ald + (size_t)node * 4);

    float4 acc4 = make_float4(0.f, 0.f, 0.f, 0.f);
    float csum = 0.f;                            // softmax denominator (per head)

    for (int base = 0; base < deg; base += 64) {
        int cnt = min(64, deg - base);
        float ex0 = 0.f, ex1 = 0.f, ex2 = 0.f, ex3 = 0.f;
        int s = 0;
        if (lane < cnt) {
            const unsigned int* row = ale_csr + (size_t)(start + base + lane) * ROW_W;
            uint2 alew = *(const uint2*)(row + 2 * layer);
            s = (int)row[6];
            float2 e01 = __half22float2(*(const __half2*)&alew.x);
            float2 e23 = __half22float2(*(const __half2*)&alew.y);
            float4 as4 = *(const float4*)(als + (size_t)s * 4);
            float v0 = as4.x + ad4.x + e01.x;
            float v1 = as4.y + ad4.y + e01.y;
            float v2 = as4.z + ad4.z + e23.x;
            float v3 = as4.w + ad4.w + e23.y;
            ex0 = expf((v0 >= 0.f) ? v0 : NEG_SLOPE * v0);
            ex1 = expf((v1 >= 0.f) ? v1 : NEG_SLOPE * v1);
            ex2 = expf((v2 >= 0.f) ? v2 : NEG_SLOPE * v2);
            ex3 = expf((v3 >= 0.f) ? v3 : NEG_SLOPE * v3);
        }
        // stage coefficients + src ids in LDS (per-wave region, wave-synchronous)
        *(float4*)(exl + wb4 + lane * 4) = make_float4(ex0, ex1, ex2, ex3);
        coll[wb + lane] = s;
        // ---- phase 3: round-up loop; indices <= eg+16*(ceil(cnt/16)-1)+12 <= 63 ----
        const float* exw = exl + wb4 + hv;
        int cntUp = (cnt + 15) & ~15;
        for (int j = eg; j < cntUp; j += 16) {
            int s0 = coll[wb + j],     s1 = coll[wb + j + 4];
            int s2 = coll[wb + j + 8], s3 = coll[wb + j + 12];
            float c0 = exw[(j) * 4],      c1 = exw[(j + 4) * 4];
            float c2 = exw[(j + 8) * 4],  c3 = exw[(j + 12) * 4];
            uint2 x0 = *(const uint2*)(xp + (size_t)s0 * 64 + cq * 4);
            uint2 x1 = *(const uint2*)(xp + (size_t)s1 * 64 + cq * 4);
            uint2 x2 = *(const uint2*)(xp + (size_t)s2 * 64 + cq * 4);
            uint2 x3 = *(const uint2*)(xp + (size_t)s3 * 64 + cq * 4);
            float2 f00 = __half22float2(*(const __half2*)&x0.x);
            float2 f01 = __half22float2(*(const __half2*)&x0.y);
            float2 f10 = __half22float2(*(const __half2*)&x1.x);
            float2 f11 = __half22float2(*(const __half2*)&x1.y);
            float2 f20 = __half22float2(*(const __half2*)&x2.x);
            float2 f21 = __half22float2(*(const __half2*)&x2.y);
            float2 f30 = __half22float2(*(const __half2*)&x3.x);
            float2 f31 = __half22float2(*(const __half2*)&x3.y);
            acc4.x += c0 * f00.x + c1 * f10.x + c2 * f20.x + c3 * f30.x;
            acc4.y += c0 * f00.y + c1 * f10.y + c2 * f20.y + c3 * f30.y;
            acc4.z += c0 * f01.x + c1 * f11.x + c2 * f21.x + c3 * f31.x;
            acc4.w += c0 * f01.y + c1 * f11.y + c2 * f21.y + c3 * f31.y;
            csum   += c0 + c1 + c2 + c3;
        }
    }
    // reduce across the 4 edge-subgroups (lanes cq, cq+16, cq+32, cq+48)
    #pragma unroll
    for (int mk = 16; mk < 64; mk <<= 1) {
        acc4.x += __shfl_xor(acc4.x, mk);
        acc4.y += __shfl_xor(acc4.y, mk);
        acc4.z += __shfl_xor(acc4.z, mk);
        acc4.w += __shfl_xor(acc4.w, mk);
        csum   += __shfl_xor(csum, mk);
    }
    if (eg == 0) {
        float inv = 1.f / (csum + 1e-16f);
        float4 b4 = *(const float4*)(bias + cq * 4);
        float4 v;
        v.x = acc4.x * inv + b4.x;
        v.y = acc4.y * inv + b4.y;
        v.z = acc4.z * inv + b4.z;
        v.w = acc4.w * inv + b4.w;
        if (relu_flag) {
            v.x = fmaxf(v.x, 0.f); v.y = fmaxf(v.y, 0.f);
            v.z = fmaxf(v.z, 0.f); v.w = fmaxf(v.w, 0.f);
        }
        *(float4*)(out + (size_t)node * 64 + cq * 4) = v;
    }
}

// ---- graph mean pool, stage 1: per-thread partial sums with
// flush-on-graph-change (batch sorted -> 1-2 atomicAdds/thread).
__global__ void pool_kernel(const float* __restrict__ h, const int* __restrict__ batch,
                            float* __restrict__ pooled) {
    int base = blockIdx.x * POOL_NODES_PER_BLK;
    int tid = threadIdx.x;
    int c = tid & 63, r = tid >> 6;
    float acc = 0.f;
    int curg = -1;
    for (int i = r; i < POOL_NODES_PER_BLK; i += 4) {
        int n = base + i;
        if (n >= N_NODES) break;
        int g = batch[n];
        if (g != curg) {
            if (curg >= 0) atomicAdd(&pooled[curg * 64 + c], acc);
            curg = g; acc = 0.f;
        }
        acc += h[(size_t)n * 64 + c];
    }
    if (curg >= 0) atomicAdd(&pooled[curg * 64 + c], acc);
}

// MLP head; divides the pooled SUM by the graph node count.
__global__ void mlp_kernel(const float* __restrict__ pooled, const int* __restrict__ batch,
                           const float* __restrict__ w1, const float* __restrict__ b1,
                           const float* __restrict__ w2, const float* __restrict__ b2,
                           float* __restrict__ y) {
    int g = blockIdx.x, t = threadIdx.x;
    __shared__ float p[64], f1[32];
    __shared__ float invc_s;
    if (t == 0) {
        int lo = 0, hi = N_NODES;
        while (lo < hi) { int mid = (lo + hi) >> 1; if (batch[mid] < g) lo = mid + 1; else hi = mid; }
        int start = lo;
        hi = N_NODES;
        while (lo < hi) { int mid = (lo + hi) >> 1; if (batch[mid] < g + 1) lo = mid + 1; else hi = mid; }
        invc_s = 1.f / fmaxf((float)(lo - start), 1.f);
    }
    __syncthreads();
    p[t] = pooled[g * 64 + t] * invc_s;
    __syncthreads();
    if (t < 32) {
        float a = b1[t];
        #pragma unroll
        for (int k = 0; k < 64; ++k) a += p[k] * w1[k * 32 + t];
        f1[t] = fmaxf(a, 0.f);
    }
    __syncthreads();
    if (t < 2) {
        float a = b2[t];
        #pragma unroll
        for (int k = 0; k < 32; ++k) a += f1[k] * w2[k * 2 + t];
        y[g * 2 + t] = a;
    }
}

extern "C" void kernel_launch(void* const* d_in, const int* in_sizes, int n_in,
                              void* d_out, int out_size, void* d_ws, size_t ws_size,
                              hipStream_t stream) {
    const float* x    = (const float*)d_in[0];
    const int*   ei   = (const int*)d_in[1];
    const float* ea   = (const float*)d_in[2];
    const int*   batch= (const int*)d_in[3];
    const float* W0   = (const float*)d_in[4];
    const float* as0  = (const float*)d_in[5];
    const float* ad0  = (const float*)d_in[6];
    const float* We0  = (const float*)d_in[7];
    const float* ae0  = (const float*)d_in[8];
    const float* b0   = (const float*)d_in[9];
    const float* Wh   = (const float*)d_in[10];
    const float* ash  = (const float*)d_in[11];
    const float* adh  = (const float*)d_in[12];
    const float* Weh  = (const float*)d_in[13];
    const float* aeh  = (const float*)d_in[14];
    const float* bh   = (const float*)d_in[15];
    const float* w1   = (const float*)d_in[16];
    const float* b1   = (const float*)d_in[17];
    const float* w2   = (const float*)d_in[18];
    const float* b2   = (const float*)d_in[19];
    float* out = (float*)d_out;

    char* wsb = (char*)d_ws;
    size_t off = 0;
    auto alloc = [&](size_t bytes) { char* p = wsb + off; off += (bytes + 255) & ~(size_t)255; return p; };
    int*          row_ptr = (int*)alloc((size_t)(N_NODES + 1) * 4);
    unsigned int* ale_csr = (unsigned int*)alloc((size_t)E_SL * ROW_W * 4);  // 54.4 MB
    float*        als     = (float*)alloc((size_t)N_NODES * 4 * 4);
    float*        ald     = (float*)alloc((size_t)N_NODES * 4 * 4);
    float*        weff    = (float*)alloc(3 * 32 * 4);
    float*        pooled  = (float*)alloc((size_t)NUM_GRAPHS * 64 * 4);
    __half*       bufA    = (__half*)alloc((size_t)N_NODES * 64 * 2);  // xp (fp16)
    float*        bufB    = (float*)alloc((size_t)N_NODES * 64 * 4);   // h (fp32)
    // CSR-build scratch ALIASED into bufB (dead before gat_node writes bufB)
    int* cnt    = (int*)bufB;
    int* cursor = cnt + N_NODES;     // contiguous with cnt -> single memset
    int* bsum   = cursor + N_NODES;

    // ---- CSR build (once): weff first (build_csr consumes it) ----
    weff_all_kernel<<<1, 128, 0, stream>>>(We0, ae0, Weh, aeh, weff);
    hipMemsetAsync(cnt, 0, (size_t)2 * N_NODES * 4, stream);   // cnt + cursor
    hist_kernel<<<(N_EDGES + 1023) / 1024, 256, 0, stream>>>(ei, cnt);
    scan_local_kernel<<<SCAN_NB, 256, 0, stream>>>(cnt, row_ptr, bsum);
    scan_bsum_kernel<<<1, 64, 0, stream>>>(bsum);
    scan_add_kernel<<<(N_NODES + 256) / 256, 256, 0, stream>>>(row_ptr, bsum);
    build_csr_kernel<<<(N_EDGES + 1023) / 1024, 256, 0, stream>>>(
        ei, ea, row_ptr, cursor, weff, ale_csr);
    mean_ea_kernel<<<(N_NODES * 2 + 255) / 256, 256, 0, stream>>>(row_ptr, ale_csr);

    // ---- 3 GAT layers (xin -> bufA(xp fp16) -> bufB(h); bufB feeds next layer) ----
    for (int layer = 0; layer < 3; ++layer) {
        const float *W, *as_, *ad_, *bb, *xin;
        int relu_flag = (layer == 0);
        if (layer == 0) {
            W = W0; as_ = as0; ad_ = ad0; bb = b0; xin = x;
        } else {
            int i = layer - 1;
            W   = Wh  + (size_t)i * 64 * 64;
            as_ = ash + (size_t)i * 64;
            ad_ = adh + (size_t)i * 64;
            bb  = bh  + (size_t)i * 64;
            xin = bufB;
        }
        int xpgrid = (N_NODES + XP_NODES_PER_BLK - 1) / XP_NODES_PER_BLK;
        if (layer == 0)
            xp_kernel<32><<<xpgrid, 64, 0, stream>>>(xin, W, as_, ad_, bufA, als, ald);
        else
            xp_kernel<64><<<xpgrid, 64, 0, stream>>>(xin, W, as_, ad_, bufA, als, ald);
        gat_node_kernel<<<(N_NODES + 3) / 4, 256, 0, stream>>>(
            row_ptr, ale_csr, als, ald, bufA, layer, bufB, bb, relu_flag);
    }
    hipMemsetAsync(pooled, 0, (size_t)NUM_GRAPHS * 64 * 4, stream);
    pool_kernel<<<(N_NODES + POOL_NODES_PER_BLK - 1) / POOL_NODES_PER_BLK, 256, 0, stream>>>(
        bufB, batch, pooled);
    mlp_kernel<<<NUM_GRAPHS, 64, 0, stream>>>(pooled, batch, w1, b1, w2, b2, out);
}

// Round 13
// 625.397 us; speedup vs baseline: 1.0584x; 1.0584x over previous
//
#include <hip/hip_runtime.h>
#include <hip/hip_bf16.h>
#include <hip/hip_fp16.h>

#define N_NODES 100000
#define N_EDGES 1600000
#define E_SL (N_EDGES + N_NODES)
#define HID 64
#define NUM_GRAPHS 64
#define NEG_SLOPE 0.2f
#define SCAN_CHUNK 1024
#define SCAN_NB ((N_NODES + SCAN_CHUNK - 1) / SCAN_CHUNK)
// CSR row: 8 words = 32B, line-aligned:
// w0=ale0.h01 w1=ale0.h23 w2=ale1.h01 w3=ale1.h23 w4=ale2.h01 w5=ale2.h23 w6=src w7=pad
#define ROW_W 8
#define XP_NODES_PER_BLK 16
#define POOL_NODES_PER_BLK 256

// ============ CSR build (once per call, reused by all 3 layers) ============

// hist + rank capture: the atomic's return value IS the edge's slot rank
// within its dst segment. Stored coalesced; build_csr then needs NO atomic
// (R12 lesson: at VALUBusy ~3% / occupancy ~50% the scatter is bound by
// random-access machinery -- remove accesses, don't add per-thread ILP).
__global__ void hist_kernel(const int* __restrict__ ei, int* __restrict__ cnt,
                            int* __restrict__ rank) {
    int e = blockIdx.x * blockDim.x + threadIdx.x;
    if (e >= N_EDGES) return;
    rank[e] = atomicAdd(&cnt[ei[N_EDGES + e]], 1);
}

__global__ void scan_local_kernel(const int* __restrict__ cnt, int* __restrict__ row_ptr,
                                  int* __restrict__ bsum) {
    __shared__ int s[256];
    int t = threadIdx.x;
    int base = blockIdx.x * SCAN_CHUNK + t * 4;
    int v[4]; int sum = 0;
    #pragma unroll
    for (int i = 0; i < 4; ++i) {
        int idx = base + i;
        v[i] = (idx < N_NODES) ? cnt[idx] + 1 : 0;
        sum += v[i];
    }
    s[t] = sum;
    __syncthreads();
    for (int off = 1; off < 256; off <<= 1) {
        int x = (t >= off) ? s[t - off] : 0;
        __syncthreads();
        s[t] += x;
        __syncthreads();
    }
    int run = s[t] - sum;
    #pragma unroll
    for (int i = 0; i < 4; ++i) {
        int idx = base + i;
        if (idx < N_NODES) row_ptr[idx] = run;
        run += v[i];
    }
    if (t == 255) bsum[blockIdx.x] = s[255];
}

__global__ void scan_bsum_kernel(int* __restrict__ bsum) {
    if (threadIdx.x != 0) return;
    int acc = 0;
    for (int i = 0; i < SCAN_NB; ++i) { int v = bsum[i]; bsum[i] = acc; acc += v; }
}

__global__ void scan_add_kernel(int* __restrict__ row_ptr, const int* __restrict__ bsum) {
    int i = blockIdx.x * blockDim.x + threadIdx.x;
    if (i > N_NODES) return;
    if (i == N_NODES) row_ptr[i] = E_SL;
    else row_ptr[i] += bsum[i >> 10];
}

// fold We (8x64) + att_e (4x16) into weff[layer][8][4] for all 3 layers.
__global__ void weff_all_kernel(const float* __restrict__ We0, const float* __restrict__ ae0,
                                const float* __restrict__ Weh, const float* __restrict__ aeh,
                                float* __restrict__ weff) {
    int t = threadIdx.x;
    if (t >= 96) return;
    int layer = t >> 5, r = t & 31;
    int dd = r >> 2, h = r & 3;
    const float* We = (layer == 0) ? We0 : Weh + (size_t)(layer - 1) * 8 * 64;
    const float* ae = (layer == 0) ? ae0 : aeh + (size_t)(layer - 1) * 64;
    float s = 0.f;
    #pragma unroll
    for (int c = 0; c < 16; ++c) s += We[dd * 64 + h * 16 + c] * ae[h * 16 + c];
    weff[layer * 32 + dd * 4 + h] = s;
}

// CSR build v5: ONE edge per thread, NO atomic (pos = row_ptr[d] + rank[e],
// rank captured in hist). Per edge: ONE random read (row_ptr line) + ONE
// random 32B row store (1 dirty line -- the scatter floor). ale[l][h] =
// ea . weff[l][:,h] precomputed for all 3 layers, packed to half.
__global__ void build_csr_kernel(const int* __restrict__ ei, const float* __restrict__ ea,
                                 const int* __restrict__ row_ptr,
                                 const int* __restrict__ rank,
                                 const float* __restrict__ weff,
                                 unsigned int* __restrict__ ale_csr) {
    int e = blockIdx.x * blockDim.x + threadIdx.x;
    if (e >= N_EDGES) return;
    int src = ei[e];
    int d = ei[N_EDGES + e];
    float4 a0 = *(const float4*)(ea + (size_t)e * 8);
    float4 a1 = *(const float4*)(ea + (size_t)e * 8 + 4);
    float av[8] = {a0.x, a0.y, a0.z, a0.w, a1.x, a1.y, a1.z, a1.w};
    unsigned int w[8];
    #pragma unroll
    for (int l = 0; l < 3; ++l) {
        float al[4];
        #pragma unroll
        for (int h = 0; h < 4; ++h) {
            float s = 0.f;
            #pragma unroll
            for (int j = 0; j < 8; ++j) s += av[j] * weff[l * 32 + j * 4 + h];
            al[h] = s;
        }
        __half2 p01 = __floats2half2_rn(al[0], al[1]);
        __half2 p23 = __floats2half2_rn(al[2], al[3]);
        w[2 * l]     = *(unsigned int*)&p01;
        w[2 * l + 1] = *(unsigned int*)&p23;
    }
    w[6] = (unsigned int)src;
    w[7] = 0u;
    int pos = row_ptr[d] + rank[e];
    unsigned int* rowp = ale_csr + (size_t)pos * ROW_W;
    *(uint4*)rowp       = make_uint4(w[0], w[1], w[2], w[3]);
    *(uint4*)(rowp + 4) = make_uint4(w[4], w[5], w[6], w[7]);
}

// self-loop row (last slot per segment) = MEAN of incoming ale rows (valid by
// linearity) + src=n. 2 threads/node.
__global__ void mean_ea_kernel(const int* __restrict__ row_ptr,
                               unsigned int* __restrict__ ale_csr) {
    int idx = blockIdx.x * blockDim.x + threadIdx.x;
    if (idx >= N_NODES * 2) return;
    int n = idx >> 1, part = idx & 1;
    int start = row_ptr[n], last = row_ptr[n + 1] - 1;
    float inv = 1.f / fmaxf((float)(last - start), 1.f);
    if (part == 0) {
        float s[8] = {0.f, 0.f, 0.f, 0.f, 0.f, 0.f, 0.f, 0.f};
        for (int pos = start; pos < last; ++pos) {
            uint4 v = *(const uint4*)(ale_csr + (size_t)pos * ROW_W);
            float2 f0 = __half22float2(*(const __half2*)&v.x);
            float2 f1 = __half22float2(*(const __half2*)&v.y);
            float2 f2 = __half22float2(*(const __half2*)&v.z);
            float2 f3 = __half22float2(*(const __half2*)&v.w);
            s[0] += f0.x; s[1] += f0.y; s[2] += f1.x; s[3] += f1.y;
            s[4] += f2.x; s[5] += f2.y; s[6] += f3.x; s[7] += f3.y;
        }
        __half2 p0 = __floats2half2_rn(s[0] * inv, s[1] * inv);
        __half2 p1 = __floats2half2_rn(s[2] * inv, s[3] * inv);
        __half2 p2 = __floats2half2_rn(s[4] * inv, s[5] * inv);
        __half2 p3 = __floats2half2_rn(s[6] * inv, s[7] * inv);
        *(uint4*)(ale_csr + (size_t)last * ROW_W) =
            make_uint4(*(unsigned int*)&p0, *(unsigned int*)&p1,
                       *(unsigned int*)&p2, *(unsigned int*)&p3);
    } else {
        float s[4] = {0.f, 0.f, 0.f, 0.f};
        for (int pos = start; pos < last; ++pos) {
            uint2 v = *(const uint2*)(ale_csr + (size_t)pos * ROW_W + 4);
            float2 f0 = __half22float2(*(const __half2*)&v.x);
            float2 f1 = __half22float2(*(const __half2*)&v.y);
            s[0] += f0.x; s[1] += f0.y; s[2] += f1.x; s[3] += f1.y;
        }
        __half2 p0 = __floats2half2_rn(s[0] * inv, s[1] * inv);
        __half2 p1 = __floats2half2_rn(s[2] * inv, s[3] * inv);
        uint4 w = make_uint4(*(unsigned int*)&p0, *(unsigned int*)&p1,
                             (unsigned int)n, 0u);
        *(uint4*)(ale_csr + (size_t)last * ROW_W + 4) = w;
    }
}

// ============ per-layer kernels ============

// xp = x @ W (output FP16); als/ald fp32. One wave per block; W column in
// VGPRs, wave-uniform x-row loads.
template <int FIN>
__global__ __launch_bounds__(64) void xp_kernel(
    const float* __restrict__ xin, const float* __restrict__ W,
    const float* __restrict__ a_s, const float* __restrict__ a_d,
    __half* __restrict__ xp, float* __restrict__ als, float* __restrict__ ald) {
    int lane = threadIdx.x;
    float wcol[FIN];
    #pragma unroll
    for (int k = 0; k < FIN; ++k) wcol[k] = W[k * 64 + lane];
    float asl = a_s[lane], adl = a_d[lane];
    int n0 = blockIdx.x * XP_NODES_PER_BLK;
    #pragma unroll 1
    for (int ni = 0; ni < XP_NODES_PER_BLK; ++ni) {
        int n = n0 + ni;
        if (n >= N_NODES) return;
        const float* xr = xin + (size_t)n * FIN;
        float a0 = 0.f, a1 = 0.f, a2 = 0.f, a3 = 0.f;
        #pragma unroll
        for (int k = 0; k < FIN; k += 4) {
            float4 xv = *(const float4*)(xr + k);
            a0 += xv.x * wcol[k];     a1 += xv.y * wcol[k + 1];
            a2 += xv.z * wcol[k + 2]; a3 += xv.w * wcol[k + 3];
        }
        float acc = (a0 + a1) + (a2 + a3);
        xp[(size_t)n * 64 + lane] = __float2half(acc);
        float ps = acc * asl, pd = acc * adl;
        #pragma unroll
        for (int mk = 8; mk >= 1; mk >>= 1) {
            ps += __shfl_xor(ps, mk, 16);
            pd += __shfl_xor(pd, mk, 16);
        }
        if ((lane & 15) == 0) {
            als[(size_t)n * 4 + (lane >> 4)] = ps;
            ald[(size_t)n * 4 + (lane >> 4)] = pd;
        }
    }
}

// Fused GAT, one wave per node. NO max-subtraction (|logit| << 88 -> expf
// cannot overflow; identical up to rounding). Phase 1: lane = edge
// (precomputed half ale from CSR row); ex + src staged in LDS (gather
// addresses from LDS/lgkmcnt, not global/vmcnt -- R8 lesson).
// Phase 3: lane = (column-quad cq, subgroup eg); round-up stride-16 loop ->
// always 4 independent fp16 row gathers in flight, no tail.
__global__ __launch_bounds__(256) void gat_node_kernel(
    const int* __restrict__ row_ptr, const unsigned int* __restrict__ ale_csr,
    const float* __restrict__ als, const float* __restrict__ ald,
    const __half* __restrict__ xp, int layer,
    float* __restrict__ out, const float* __restrict__ bias, int relu_flag) {
    __shared__ float exl[4 * 256];   // per-wave: 64 edges x 4 heads
    __shared__ int   coll[4 * 64];   // per-wave: 64 src ids
    int wave = threadIdx.x >> 6, lane = threadIdx.x & 63;
    int node = blockIdx.x * 4 + wave;
    if (node >= N_NODES) return;
    int start = row_ptr[node], end = row_ptr[node + 1];
    int deg = end - start;                       // >= 1 (self-loop)
    int wb = wave * 64, wb4 = wave * 256;
    int cq = lane & 15;                          // column quad: cols 4cq..4cq+3
    int eg = lane >> 4;                          // edge subgroup 0..3
    int hv = cq >> 2;                            // head for this column quad

    float4 ad4 = *(const float4*)(ald + (size_t)node * 4);

    float4 acc4 = make_float4(0.f, 0.f, 0.f, 0.f);
    float csum = 0.f;                            // softmax denominator (per head)

    for (int base = 0; base < deg; base += 64) {
        int cnt = min(64, deg - base);
        float ex0 = 0.f, ex1 = 0.f, ex2 = 0.f, ex3 = 0.f;
        int s = 0;
        if (lane < cnt) {
            const unsigned int* row = ale_csr + (size_t)(start + base + lane) * ROW_W;
            uint2 alew = *(const uint2*)(row + 2 * layer);
            s = (int)row[6];
            float2 e01 = __half22float2(*(const __half2*)&alew.x);
            float2 e23 = __half22float2(*(const __half2*)&alew.y);
            float4 as4 = *(const float4*)(als + (size_t)s * 4);
            float v0 = as4.x + ad4.x + e01.x;
            float v1 = as4.y + ad4.y + e01.y;
            float v2 = as4.z + ad4.z + e23.x;
            float v3 = as4.w + ad4.w + e23.y;
            ex0 = expf((v0 >= 0.f) ? v0 : NEG_SLOPE * v0);
            ex1 = expf((v1 >= 0.f) ? v1 : NEG_SLOPE * v1);
            ex2 = expf((v2 >= 0.f) ? v2 : NEG_SLOPE * v2);
            ex3 = expf((v3 >= 0.f) ? v3 : NEG_SLOPE * v3);
        }
        // stage coefficients + src ids in LDS (per-wave region, wave-synchronous)
        *(float4*)(exl + wb4 + lane * 4) = make_float4(ex0, ex1, ex2, ex3);
        coll[wb + lane] = s;
        // ---- phase 3: round-up loop; indices <= eg+16*(ceil(cnt/16)-1)+12 <= 63 ----
        const float* exw = exl + wb4 + hv;
        int cntUp = (cnt + 15) & ~15;
        for (int j = eg; j < cntUp; j += 16) {
            int s0 = coll[wb + j],     s1 = coll[wb + j + 4];
            int s2 = coll[wb + j + 8], s3 = coll[wb + j + 12];
            float c0 = exw[(j) * 4],      c1 = exw[(j + 4) * 4];
            float c2 = exw[(j + 8) * 4],  c3 = exw[(j + 12) * 4];
            uint2 x0 = *(const uint2*)(xp + (size_t)s0 * 64 + cq * 4);
            uint2 x1 = *(const uint2*)(xp + (size_t)s1 * 64 + cq * 4);
            uint2 x2 = *(const uint2*)(xp + (size_t)s2 * 64 + cq * 4);
            uint2 x3 = *(const uint2*)(xp + (size_t)s3 * 64 + cq * 4);
            float2 f00 = __half22float2(*(const __half2*)&x0.x);
            float2 f01 = __half22float2(*(const __half2*)&x0.y);
            float2 f10 = __half22float2(*(const __half2*)&x1.x);
            float2 f11 = __half22float2(*(const __half2*)&x1.y);
            float2 f20 = __half22float2(*(const __half2*)&x2.x);
            float2 f21 = __half22float2(*(const __half2*)&x2.y);
            float2 f30 = __half22float2(*(const __half2*)&x3.x);
            float2 f31 = __half22float2(*(const __half2*)&x3.y);
            acc4.x += c0 * f00.x + c1 * f10.x + c2 * f20.x + c3 * f30.x;
            acc4.y += c0 * f00.y + c1 * f10.y + c2 * f20.y + c3 * f30.y;
            acc4.z += c0 * f01.x + c1 * f11.x + c2 * f21.x + c3 * f31.x;
            acc4.w += c0 * f01.y + c1 * f11.y + c2 * f21.y + c3 * f31.y;
            csum   += c0 + c1 + c2 + c3;
        }
    }
    // reduce across the 4 edge-subgroups (lanes cq, cq+16, cq+32, cq+48)
    #pragma unroll
    for (int mk = 16; mk < 64; mk <<= 1) {
        acc4.x += __shfl_xor(acc4.x, mk);
        acc4.y += __shfl_xor(acc4.y, mk);
        acc4.z += __shfl_xor(acc4.z, mk);
        acc4.w += __shfl_xor(acc4.w, mk);
        csum   += __shfl_xor(csum, mk);
    }
    if (eg == 0) {
        float inv = 1.f / (csum + 1e-16f);
        float4 b4 = *(const float4*)(bias + cq * 4);
        float4 v;
        v.x = acc4.x * inv + b4.x;
        v.y = acc4.y * inv + b4.y;
        v.z = acc4.z * inv + b4.z;
        v.w = acc4.w * inv + b4.w;
        if (relu_flag) {
            v.x = fmaxf(v.x, 0.f); v.y = fmaxf(v.y, 0.f);
            v.z = fmaxf(v.z, 0.f); v.w = fmaxf(v.w, 0.f);
        }
        *(float4*)(out + (size_t)node * 64 + cq * 4) = v;
    }
}

// ---- graph mean pool, stage 1: per-thread partial sums with
// flush-on-graph-change (batch sorted -> 1-2 atomicAdds/thread).
__global__ void pool_kernel(const float* __restrict__ h, const int* __restrict__ batch,
                            float* __restrict__ pooled) {
    int base = blockIdx.x * POOL_NODES_PER_BLK;
    int tid = threadIdx.x;
    int c = tid & 63, r = tid >> 6;
    float acc = 0.f;
    int curg = -1;
    for (int i = r; i < POOL_NODES_PER_BLK; i += 4) {
        int n = base + i;
        if (n >= N_NODES) break;
        int g = batch[n];
        if (g != curg) {
            if (curg >= 0) atomicAdd(&pooled[curg * 64 + c], acc);
            curg = g; acc = 0.f;
        }
        acc += h[(size_t)n * 64 + c];
    }
    if (curg >= 0) atomicAdd(&pooled[curg * 64 + c], acc);
}

// MLP head; divides the pooled SUM by the graph node count.
__global__ void mlp_kernel(const float* __restrict__ pooled, const int* __restrict__ batch,
                           const float* __restrict__ w1, const float* __restrict__ b1,
                           const float* __restrict__ w2, const float* __restrict__ b2,
                           float* __restrict__ y) {
    int g = blockIdx.x, t = threadIdx.x;
    __shared__ float p[64], f1[32];
    __shared__ float invc_s;
    if (t == 0) {
        int lo = 0, hi = N_NODES;
        while (lo < hi) { int mid = (lo + hi) >> 1; if (batch[mid] < g) lo = mid + 1; else hi = mid; }
        int start = lo;
        hi = N_NODES;
        while (lo < hi) { int mid = (lo + hi) >> 1; if (batch[mid] < g + 1) lo = mid + 1; else hi = mid; }
        invc_s = 1.f / fmaxf((float)(lo - start), 1.f);
    }
    __syncthreads();
    p[t] = pooled[g * 64 + t] * invc_s;
    __syncthreads();
    if (t < 32) {
        float a = b1[t];
        #pragma unroll
        for (int k = 0; k < 64; ++k) a += p[k] * w1[k * 32 + t];
        f1[t] = fmaxf(a, 0.f);
    }
    __syncthreads();
    if (t < 2) {
        float a = b2[t];
        #pragma unroll
        for (int k = 0; k < 32; ++k) a += f1[k] * w2[k * 2 + t];
        y[g * 2 + t] = a;
    }
}

extern "C" void kernel_launch(void* const* d_in, const int* in_sizes, int n_in,
                              void* d_out, int out_size, void* d_ws, size_t ws_size,
                              hipStream_t stream) {
    const float* x    = (const float*)d_in[0];
    const int*   ei   = (const int*)d_in[1];
    const float* ea   = (const float*)d_in[2];
    const int*   batch= (const int*)d_in[3];
    const float* W0   = (const float*)d_in[4];
    const float* as0  = (const float*)d_in[5];
    const float* ad0  = (const float*)d_in[6];
    const float* We0  = (const float*)d_in[7];
    const float* ae0  = (const float*)d_in[8];
    const float* b0   = (const float*)d_in[9];
    const float* Wh   = (const float*)d_in[10];
    const float* ash  = (const float*)d_in[11];
    const float* adh  = (const float*)d_in[12];
    const float* Weh  = (const float*)d_in[13];
    const float* aeh  = (const float*)d_in[14];
    const float* bh   = (const float*)d_in[15];
    const float* w1   = (const float*)d_in[16];
    const float* b1   = (const float*)d_in[17];
    const float* w2   = (const float*)d_in[18];
    const float* b2   = (const float*)d_in[19];
    float* out = (float*)d_out;

    char* wsb = (char*)d_ws;
    size_t off = 0;
    auto alloc = [&](size_t bytes) { char* p = wsb + off; off += (bytes + 255) & ~(size_t)255; return p; };
    int*          row_ptr = (int*)alloc((size_t)(N_NODES + 1) * 4);
    unsigned int* ale_csr = (unsigned int*)alloc((size_t)E_SL * ROW_W * 4);  // 54.4 MB
    float*        als     = (float*)alloc((size_t)N_NODES * 4 * 4);
    float*        ald     = (float*)alloc((size_t)N_NODES * 4 * 4);
    float*        weff    = (float*)alloc(3 * 32 * 4);
    float*        pooled  = (float*)alloc((size_t)NUM_GRAPHS * 64 * 4);
    __half*       bufA    = (__half*)alloc((size_t)N_NODES * 64 * 2);  // xp (fp16)
    float*        bufB    = (float*)alloc((size_t)N_NODES * 64 * 4);   // h (fp32)
    // CSR-build scratch ALIASED into bufB (dead before gat_node writes bufB):
    // cnt (400KB) + bsum + rank (6.4MB) < 25.6MB
    int* cnt  = (int*)bufB;
    int* bsum = cnt + N_NODES;
    int* rank = bsum + ((SCAN_NB + 63) & ~63);

    // ---- CSR build (once): weff first (build_csr consumes it) ----
    weff_all_kernel<<<1, 128, 0, stream>>>(We0, ae0, Weh, aeh, weff);
    hipMemsetAsync(cnt, 0, (size_t)N_NODES * 4, stream);
    hist_kernel<<<(N_EDGES + 255) / 256, 256, 0, stream>>>(ei, cnt, rank);
    scan_local_kernel<<<SCAN_NB, 256, 0, stream>>>(cnt, row_ptr, bsum);
    scan_bsum_kernel<<<1, 64, 0, stream>>>(bsum);
    scan_add_kernel<<<(N_NODES + 256) / 256, 256, 0, stream>>>(row_ptr, bsum);
    build_csr_kernel<<<(N_EDGES + 255) / 256, 256, 0, stream>>>(
        ei, ea, row_ptr, rank, weff, ale_csr);
    mean_ea_kernel<<<(N_NODES * 2 + 255) / 256, 256, 0, stream>>>(row_ptr, ale_csr);

    // ---- 3 GAT layers (xin -> bufA(xp fp16) -> bufB(h); bufB feeds next layer) ----
    for (int layer = 0; layer < 3; ++layer) {
        const float *W, *as_, *ad_, *bb, *xin;
        int relu_flag = (layer == 0);
        if (layer == 0) {
            W = W0; as_ = as0; ad_ = ad0; bb = b0; xin = x;
        } else {
            int i = layer - 1;
            W   = Wh  + (size_t)i * 64 * 64;
            as_ = ash + (size_t)i * 64;
            ad_ = adh + (size_t)i * 64;
            bb  = bh  + (size_t)i * 64;
            xin = bufB;
        }
        int xpgrid = (N_NODES + XP_NODES_PER_BLK - 1) / XP_NODES_PER_BLK;
        if (layer == 0)
            xp_kernel<32><<<xpgrid, 64, 0, stream>>>(xin, W, as_, ad_, bufA, als, ald);
        else
            xp_kernel<64><<<xpgrid, 64, 0, stream>>>(xin, W, as_, ad_, bufA, als, ald);
        gat_node_kernel<<<(N_NODES + 3) / 4, 256, 0, stream>>>(
            row_ptr, ale_csr, als, ald, bufA, layer, bufB, bb, relu_flag);
    }
    hipMemsetAsync(pooled, 0, (size_t)NUM_GRAPHS * 64 * 4, stream);
    pool_kernel<<<(N_NODES + POOL_NODES_PER_BLK - 1) / POOL_NODES_PER_BLK, 256, 0, stream>>>(
        bufB, batch, pooled);
    mlp_kernel<<<NUM_GRAPHS, 64, 0, stream>>>(pooled, batch, w1, b1, w2, b2, out);
}